// Round 1
// baseline (313.991 us; speedup 1.0000x reference)
//
#include <hip/hip_runtime.h>

#define B_  16
#define T_  2500
#define X_  512
#define WT  101
#define RT  50
#define WX  11
#define RX  5
#define BT  8
#define NSTRIP ((T_ + BT - 1) / BT)   // 313

// Fused kernel: per block = one batch image, one strip of BT output rows, all 512 cols.
// Pass A (registers): T-direction 101-tap conv of the 5 product fields, input-stationary:
//   loop over the 108 contributing input rows; each row scatters into the 8 row-accumulators
//   with a shift-register of wave-uniform weights (zero-padded kt table -> no branches,
//   all register indices compile-time static).
// Pass B (LDS, per output row): 11-tap X conv + coherence math + local sum.
// Block partial sums -> d_ws; second kernel reduces to the scalar mean.
__global__ __launch_bounds__(256) void coh_main(const float* __restrict__ xg,
                                                const float* __restrict__ yg,
                                                float* __restrict__ partial) {
    __shared__ float kt_pad[120];                 // index j - rl + 7, j in [0,107], rl in [0,7]
    __shared__ float kx_s[WX];
    __shared__ float rowbuf[5][X_ + 2 * RX + 2];  // 522 used (+2 pad), zeroed halo
    __shared__ float wred[4];
    __shared__ float norm[2];

    const int tid = threadIdx.x;
    const int b   = blockIdx.x;
    const int t0  = blockIdx.y * BT;

    // ---- build normalized Gaussian kernels in LDS (cheap, per block) ----
    if (tid < 120) kt_pad[tid] = 0.0f;
    if (tid < WT) {
        float d = (float)(tid - RT);
        kt_pad[tid + 7] = expf(-d * d / (2.0f * 21.0f * 21.0f));
    }
    if (tid < WX) {
        float d = (float)(tid - RX);
        kx_s[tid] = expf(-d * d / (2.0f * 11.0f * 11.0f));
    }
    __syncthreads();
    if (tid == 0) {
        float s = 0.0f;
        for (int i = 0; i < WT; ++i) s += kt_pad[i + 7];
        norm[0] = 1.0f / s;
        s = 0.0f;
        for (int i = 0; i < WX; ++i) s += kx_s[i];
        norm[1] = 1.0f / s;
    }
    __syncthreads();
    if (tid < WT) kt_pad[tid + 7] *= norm[0];
    if (tid < WX) kx_s[tid] *= norm[1];
    __syncthreads();

    // ---- Pass A: T-conv into register accumulators ----
    const float2* xrow = (const float2*)(xg + (size_t)b * T_ * X_);
    const float2* yrow = (const float2*)(yg + (size_t)b * T_ * X_);

    float acc[5][BT][2];
#pragma unroll
    for (int f = 0; f < 5; ++f)
#pragma unroll
        for (int r = 0; r < BT; ++r) { acc[f][r][0] = 0.0f; acc[f][r][1] = 0.0f; }

    float w[BT];
#pragma unroll
    for (int r = 0; r < BT; ++r) w[r] = 0.0f;

    // prefetch row j=0
    float2 xv_n = make_float2(0.0f, 0.0f), yv_n = make_float2(0.0f, 0.0f);
    {
        int tau = t0 - RT;
        if (tau >= 0 && tau < T_) {
            xv_n = xrow[(size_t)tau * (X_ / 2) + tid];
            yv_n = yrow[(size_t)tau * (X_ / 2) + tid];
        }
    }

#pragma unroll 4
    for (int j = 0; j < BT + 2 * RT; ++j) {   // 108 iterations
        float2 xv = xv_n, yv = yv_n;
        // prefetch next row
        {
            int tau = t0 - RT + j + 1;
            xv_n = make_float2(0.0f, 0.0f);
            yv_n = make_float2(0.0f, 0.0f);
            if (j + 1 < BT + 2 * RT && tau >= 0 && tau < T_) {
                xv_n = xrow[(size_t)tau * (X_ / 2) + tid];
                yv_n = yrow[(size_t)tau * (X_ / 2) + tid];
            }
        }
        // shift weight window; w[rl] = kt_pad[j - rl + 7]
#pragma unroll
        for (int r = BT - 1; r >= 1; --r) w[r] = w[r - 1];
        w[0] = kt_pad[j + 7];

        float p[5][2];
        p[0][0] = xv.x;          p[0][1] = xv.y;
        p[1][0] = yv.x;          p[1][1] = yv.y;
        p[2][0] = xv.x * xv.x;   p[2][1] = xv.y * xv.y;
        p[3][0] = yv.x * yv.x;   p[3][1] = yv.y * yv.y;
        p[4][0] = xv.x * yv.x;   p[4][1] = xv.y * yv.y;

#pragma unroll
        for (int r = 0; r < BT; ++r) {
            float ww = w[r];
#pragma unroll
            for (int f = 0; f < 5; ++f) {
                acc[f][r][0] = fmaf(ww, p[f][0], acc[f][r][0]);
                acc[f][r][1] = fmaf(ww, p[f][1], acc[f][r][1]);
            }
        }
    }

    // hoist kx into registers
    float kxr[WX];
#pragma unroll
    for (int i = 0; i < WX; ++i) kxr[i] = kx_s[i];

    // ---- Pass B: per output row, X-conv via LDS + coherence + local sum ----
    float local = 0.0f;
#pragma unroll
    for (int rl = 0; rl < BT; ++rl) {
        int t = t0 + rl;
        __syncthreads();
#pragma unroll
        for (int f = 0; f < 5; ++f) {
            rowbuf[f][RX + 2 * tid]     = acc[f][rl][0];
            rowbuf[f][RX + 2 * tid + 1] = acc[f][rl][1];
        }
        if (tid < RX) {
#pragma unroll
            for (int f = 0; f < 5; ++f) {
                rowbuf[f][tid] = 0.0f;            // left halo
                rowbuf[f][X_ + RX + tid] = 0.0f;  // right halo
            }
        }
        __syncthreads();

        if (t < T_) {
            float s0[5], s1[5];
#pragma unroll
            for (int f = 0; f < 5; ++f) {
                float vv[12];
#pragma unroll
                for (int k = 0; k < 6; ++k) {
                    float2 pr = *(const float2*)&rowbuf[f][2 * tid + 2 * k];
                    vv[2 * k]     = pr.x;
                    vv[2 * k + 1] = pr.y;
                }
                float a0 = 0.0f, a1 = 0.0f;
#pragma unroll
                for (int i = 0; i < WX; ++i) {
                    a0 = fmaf(kxr[i], vv[i], a0);
                    a1 = fmaf(kxr[i], vv[i + 1], a1);
                }
                s0[f] = a0; s1[f] = a1;
            }
            {
                float mux = s0[0], muy = s0[1];
                float vx = s0[2] - mux * mux;
                float vy = s0[3] - muy * muy;
                float cxy = s0[4] - mux * muy;
                float cs = cxy * rsqrtf(vx * vy + 1e-9f);
                local += 1.0f - cs;
            }
            {
                float mux = s1[0], muy = s1[1];
                float vx = s1[2] - mux * mux;
                float vy = s1[3] - muy * muy;
                float cxy = s1[4] - mux * muy;
                float cs = cxy * rsqrtf(vx * vy + 1e-9f);
                local += 1.0f - cs;
            }
        }
    }

    // ---- block reduction -> one partial per block ----
#pragma unroll
    for (int off = 32; off >= 1; off >>= 1) local += __shfl_down(local, off);
    if ((tid & 63) == 0) wred[tid >> 6] = local;
    __syncthreads();
    if (tid == 0)
        partial[blockIdx.y * B_ + b] = wred[0] + wred[1] + wred[2] + wred[3];
}

__global__ __launch_bounds__(256) void coh_reduce(const float* __restrict__ partial,
                                                  float* __restrict__ out) {
    __shared__ float wred[4];
    const int tid = threadIdx.x;
    float s = 0.0f;
    for (int i = tid; i < B_ * NSTRIP; i += 256) s += partial[i];
#pragma unroll
    for (int off = 32; off >= 1; off >>= 1) s += __shfl_down(s, off);
    if ((tid & 63) == 0) wred[tid >> 6] = s;
    __syncthreads();
    if (tid == 0)
        out[0] = (wred[0] + wred[1] + wred[2] + wred[3]) *
                 (1.0f / ((float)B_ * (float)T_ * (float)X_));
}

extern "C" void kernel_launch(void* const* d_in, const int* in_sizes, int n_in,
                              void* d_out, int out_size, void* d_ws, size_t ws_size,
                              hipStream_t stream) {
    const float* x = (const float*)d_in[0];
    const float* y = (const float*)d_in[1];
    float* out = (float*)d_out;
    float* partial = (float*)d_ws;   // B_*NSTRIP floats = ~20 KB

    dim3 grid(B_, NSTRIP);
    coh_main<<<grid, 256, 0, stream>>>(x, y, partial);
    coh_reduce<<<1, 256, 0, stream>>>(partial, out);
}

// Round 2
// 234.589 us; speedup vs baseline: 1.3385x; 1.3385x over previous
//
#include <hip/hip_runtime.h>
#include <hip/hip_bf16.h>

#define B_  16
#define T_  2500
#define X_  512
#define XT  32                     // output cols per block
#define MT  64                     // output rows per block (4 waves x 16)
#define NSX (X_ / XT)              // 16
#define NST ((T_ + MT - 1) / MT)   // 40
#define NBLK (B_ * NST * NSX)      // 10240

typedef __attribute__((ext_vector_type(8))) short short8;   // 8 bf16 (4 VGPRs)
typedef __attribute__((ext_vector_type(4))) float f32x4;    // 4 fp32 acc

__device__ __forceinline__ ushort f2bf(float f) {
    __hip_bfloat16 h = __float2bfloat16(f);
    return __builtin_bit_cast(ushort, h);
}

// Pipeline per block (b, t-strip of 64 rows, x-tile of 32 cols):
//  for each 16-row staging chunk s (11 chunks cover rows t0-56 .. t0+119):
//    stage:  load x,y, form 5 products, bf16 -> PB[5][16][48]        (all thr)
//    xconv:  MFMA A_kx(16x32 band) * PB -> X-smoothed D, bf16 -> BB ring
//    tconv:  waves whose K-chunk just completed: MFMA A_kt * BB -> acc
//  pointwise coherence on acc (D-layout: col=lane&15, row=(lane>>4)*4+r),
//  block-reduce (1-cs) -> partial; tiny second kernel -> mean.
__global__ __launch_bounds__(256) void coh_mfma(const float* __restrict__ xg,
                                                const float* __restrict__ yg,
                                                float* __restrict__ partial)
{
    __shared__ float ktn[104];
    __shared__ float kxn[12];
    __shared__ float norm2[2];
    __shared__ short PB[5][16][48];      // bf16 products, one 16-row chunk
    __shared__ short BB[8][5][32][8];    // ring: [rowgrp&7][f][col][slot] bf16
    __shared__ float wred[4];

    const int tid  = threadIdx.x;
    const int lane = tid & 63;
    const int w    = tid >> 6;       // wave 0..3
    const int g    = lane >> 4;      // quarter-wave 0..3
    const int ln16 = lane & 15;

    const int x0   = blockIdx.x * XT;
    const int t0   = blockIdx.y * MT;
    const int b    = blockIdx.z;
    const int tauB = t0 - 56;        // first staged input row (8-aligned offset)

    // ---- build normalized Gaussian tables ----
    if (tid < 104) ktn[tid] = 0.0f;
    if (tid < 12)  kxn[tid] = 0.0f;
    __syncthreads();
    if (tid < 101) { float d = (float)(tid - 50); ktn[tid] = expf(-d * d / (2.0f * 21.0f * 21.0f)); }
    if (tid < 11)  { float d = (float)(tid - 5);  kxn[tid] = expf(-d * d / (2.0f * 11.0f * 11.0f)); }
    __syncthreads();
    if (tid == 0) {
        float s = 0.f; for (int i = 0; i < 101; ++i) s += ktn[i]; norm2[0] = 1.0f / s;
        s = 0.f;       for (int i = 0; i < 11;  ++i) s += kxn[i]; norm2[1] = 1.0f / s;
    }
    __syncthreads();
    if (tid < 101) ktn[tid] *= norm2[0];
    if (tid < 11)  kxn[tid] *= norm2[1];
    __syncthreads();

    // ---- wave-uniform banded weight fragments (A operands) ----
    // Consistent k-slot convention for A and B: slot s of lane-group g <-> k = 8g+s.
    short8 a_t[4];
#pragma unroll
    for (int c = 0; c < 4; ++c)
#pragma unroll
        for (int sl = 0; sl < 8; ++sl) {
            int idx = 32 * c + 8 * g + sl - ln16 - 6;   // ktn index, valid 0..100
            float v = (idx >= 0 && idx <= 100) ? ktn[idx] : 0.0f;
            a_t[c][sl] = (short)f2bf(v);
        }
    short8 a_x;
#pragma unroll
    for (int sl = 0; sl < 8; ++sl) {
        int idx = 8 * g + sl - ln16 - 3;                // kxn index, valid 0..10
        float v = (idx >= 0 && idx <= 10) ? kxn[idx] : 0.0f;
        a_x[sl] = (short)f2bf(v);
    }

    f32x4 acc[5][2];
#pragma unroll
    for (int f = 0; f < 5; ++f)
#pragma unroll
        for (int u = 0; u < 2; ++u) { acc[f][u][0] = 0.f; acc[f][u][1] = 0.f; acc[f][u][2] = 0.f; acc[f][u][3] = 0.f; }

    const float* xb = xg + (size_t)b * T_ * X_;
    const float* yb = yg + (size_t)b * T_ * X_;

    for (int s = 0; s < 11; ++s) {
        // ---- stage chunk s: 16 rows x 24 col-pairs (cols x0-8 .. x0+39) ----
#pragma unroll
        for (int q = 0; q < 2; ++q) {
            int P = tid + q * 256;
            if (P < 384) {
                int rr = P / 24;
                int p  = P - rr * 24;
                int grow = tauB + 16 * s + rr;
                int gcol = x0 - 8 + 2 * p;               // even -> pair fully in or out
                float2 xv = {0.f, 0.f}, yv = {0.f, 0.f};
                if (grow >= 0 && grow < T_ && gcol >= 0 && gcol < X_) {
                    xv = *(const float2*)(xb + (size_t)grow * X_ + gcol);
                    yv = *(const float2*)(yb + (size_t)grow * X_ + gcol);
                }
                uint v0 = (uint)f2bf(xv.x)        | ((uint)f2bf(xv.y)        << 16);
                uint v1 = (uint)f2bf(yv.x)        | ((uint)f2bf(yv.y)        << 16);
                uint v2 = (uint)f2bf(xv.x * xv.x) | ((uint)f2bf(xv.y * xv.y) << 16);
                uint v3 = (uint)f2bf(yv.x * yv.x) | ((uint)f2bf(yv.y * yv.y) << 16);
                uint v4 = (uint)f2bf(xv.x * yv.x) | ((uint)f2bf(xv.y * yv.y) << 16);
                *(uint*)&PB[0][rr][2 * p] = v0;
                *(uint*)&PB[1][rr][2 * p] = v1;
                *(uint*)&PB[2][rr][2 * p] = v2;
                *(uint*)&PB[3][rr][2 * p] = v3;
                *(uint*)&PB[4][rr][2 * p] = v4;
            }
        }
        __syncthreads();

        // ---- X-conv MFMA for chunk s: 10 (f,u) tasks split across waves ----
        for (int t = w; t < 10; t += 4) {
            int f = t >> 1, u = t & 1;
            const short8 bfrag = *(const short8*)&PB[f][ln16][16 * u + 8 * g];
            f32x4 z; z[0] = 0.f; z[1] = 0.f; z[2] = 0.f; z[3] = 0.f;
            f32x4 d = __builtin_amdgcn_mfma_f32_16x16x32_bf16(a_x, bfrag, z, 0, 0, 0);
            // D: row m = outcol = 4g+r, col n = t-row = ln16
            int g8 = (2 * s + (ln16 >> 3)) & 7;
            int sl = ln16 & 7;
            int colbase = 16 * u + 4 * g;
#pragma unroll
            for (int r = 0; r < 4; ++r)
                BB[g8][f][colbase + r][sl] = (short)f2bf(d[r]);
        }
        __syncthreads();

        // ---- T-conv MFMA: wave w fires K-chunk c when s == w + 2c + 1 ----
        int sc = s - 1;
        if (sc >= 0 && (((w ^ sc) & 1) == 0)) {
#pragma unroll
            for (int c = 0; c < 4; ++c) {
                if (sc == w + 2 * c) {
#pragma unroll
                    for (int f = 0; f < 5; ++f)
#pragma unroll
                        for (int u = 0; u < 2; ++u) {
                            int g8 = (2 * w + 4 * c + g) & 7;
                            const short8 bfrag = *(const short8*)&BB[g8][f][16 * u + ln16][0];
                            acc[f][u] = __builtin_amdgcn_mfma_f32_16x16x32_bf16(a_t[c], bfrag, acc[f][u], 0, 0, 0);
                        }
                }
            }
        }
    }

    // ---- pointwise coherence + reduction ----
    float local = 0.0f;
#pragma unroll
    for (int u = 0; u < 2; ++u)
#pragma unroll
        for (int r = 0; r < 4; ++r) {
            int t = t0 + 16 * w + 4 * g + r;
            if (t < T_) {
                float mux = acc[0][u][r], muy = acc[1][u][r];
                float vx  = acc[2][u][r] - mux * mux;
                float vy  = acc[3][u][r] - muy * muy;
                float cxy = acc[4][u][r] - mux * muy;
                float cs  = cxy * rsqrtf(vx * vy + 1e-9f);
                local += 1.0f - cs;
            }
        }

#pragma unroll
    for (int off = 32; off >= 1; off >>= 1) local += __shfl_down(local, off);
    if ((tid & 63) == 0) wred[tid >> 6] = local;
    __syncthreads();
    if (tid == 0)
        partial[((size_t)b * NST + blockIdx.y) * NSX + blockIdx.x] =
            wred[0] + wred[1] + wred[2] + wred[3];
}

__global__ __launch_bounds__(256) void coh_reduce(const float* __restrict__ partial,
                                                  float* __restrict__ out) {
    __shared__ float wred[4];
    const int tid = threadIdx.x;
    float s = 0.0f;
    for (int i = tid; i < NBLK; i += 256) s += partial[i];
#pragma unroll
    for (int off = 32; off >= 1; off >>= 1) s += __shfl_down(s, off);
    if ((tid & 63) == 0) wred[tid >> 6] = s;
    __syncthreads();
    if (tid == 0)
        out[0] = (wred[0] + wred[1] + wred[2] + wred[3]) *
                 (1.0f / ((float)B_ * (float)T_ * (float)X_));
}

extern "C" void kernel_launch(void* const* d_in, const int* in_sizes, int n_in,
                              void* d_out, int out_size, void* d_ws, size_t ws_size,
                              hipStream_t stream) {
    const float* x = (const float*)d_in[0];
    const float* y = (const float*)d_in[1];
    float* out = (float*)d_out;
    float* partial = (float*)d_ws;   // NBLK floats = 40 KB

    dim3 grid(NSX, NST, B_);         // 16 x 40 x 16 = 10240 blocks
    coh_mfma<<<grid, 256, 0, stream>>>(x, y, partial);
    coh_reduce<<<1, 256, 0, stream>>>(partial, out);
}

// Round 3
// 205.354 us; speedup vs baseline: 1.5290x; 1.1424x over previous
//
#include <hip/hip_runtime.h>
#include <hip/hip_bf16.h>

#define B_   16
#define T_   2500
#define X_   512
#define XT   32
#define XH   48                 // staged cols per chunk (x0-8 .. x0+39)
#define SEGS 4
#define SEGR 640                // rows per segment (last covers 580)
#define NSX  (X_ / XT)          // 16
#define NBLK (B_ * SEGS * NSX)  // 1024

typedef __attribute__((ext_vector_type(8))) short short8;
typedef __attribute__((ext_vector_type(4))) short short4v;
typedef __attribute__((ext_vector_type(4))) float f32x4;

__device__ __forceinline__ ushort f2bf(float f) {
    __hip_bfloat16 h = __float2bfloat16(f);
    return __builtin_bit_cast(ushort, h);
}
__device__ __forceinline__ float bf2f(ushort u) {
    return __builtin_bit_cast(float, ((uint)u) << 16);
}
__device__ __forceinline__ int pcol(int c) { return c ^ ((c >> 3) & 3); }

// Streaming fused kernel. Block = (x-tile of 32 cols, T-segment of 640 rows, batch b).
// Ring XS[16 groups][5][32 cols][8 rowslots] holds bf16 X-smoothed rows (X-conv on VALU
// at stage time, so T-conv needs no X-halo). T-conv = banded K=128 MFMA (4 chunks of
// 16x16x32 bf16), round-2's verified fragment convention. Per 16-row macro-iteration:
//   1. issue next chunk's global loads (regs); tconv MFMA -> TS (f32)
//   2. barrier; products -> PB (bf16)
//   3. barrier; xconv (VALU, 11 taps) -> ring; pointwise coherence from TS -> local
//   4. barrier
__global__ __launch_bounds__(256) void coh3(const float* __restrict__ xg,
                                            const float* __restrict__ yg,
                                            float* __restrict__ partial)
{
    __shared__ float ktn[104];
    __shared__ float kxn[12];
    __shared__ float norm2[2];
    __shared__ short XS[16][5][XT][8];   // 40 KB ring
    __shared__ short PB[5][16][XH];      // 7.5 KB raw products (one 16-row chunk)
    __shared__ float TS[5][16][XT];      // 10 KB T-smoothed tile
    __shared__ float wred[4];

    const int tid  = threadIdx.x;
    const int lane = tid & 63;
    const int w    = tid >> 6;
    const int g    = lane >> 4;
    const int ln16 = lane & 15;

    const int x0    = blockIdx.x * XT;
    const int seg   = blockIdx.y;
    const int t0    = seg * SEGR;
    const int t_end = min(t0 + SEGR, T_);
    const int nm    = (t_end - t0 + 15) >> 4;
    const int b     = blockIdx.z;

    // ---- normalized Gaussian tables (once per block) ----
    if (tid < 104) ktn[tid] = 0.0f;
    if (tid < 12)  kxn[tid] = 0.0f;
    __syncthreads();
    if (tid < 101) { float d = (float)(tid - 50); ktn[tid] = expf(-d * d / (2.0f * 21.0f * 21.0f)); }
    if (tid < 11)  { float d = (float)(tid - 5);  kxn[tid] = expf(-d * d / (2.0f * 11.0f * 11.0f)); }
    __syncthreads();
    if (tid == 0) {
        float s = 0.f; for (int i = 0; i < 101; ++i) s += ktn[i]; norm2[0] = 1.0f / s;
        s = 0.f;       for (int i = 0; i < 11;  ++i) s += kxn[i]; norm2[1] = 1.0f / s;
    }
    __syncthreads();
    if (tid < 101) ktn[tid] *= norm2[0];
    if (tid < 11)  kxn[tid] *= norm2[1];
    __syncthreads();

    // ---- T-conv A fragments (banded kt), k-slot convention: slot sl of group g <-> k=8g+sl ----
    short8 a_t[4];
#pragma unroll
    for (int c = 0; c < 4; ++c)
#pragma unroll
        for (int sl = 0; sl < 8; ++sl) {
            int idx = 32 * c + 8 * g + sl - ln16 - 6;
            float v = (idx >= 0 && idx <= 100) ? ktn[idx] : 0.0f;
            a_t[c][sl] = (short)f2bf(v);
        }
    float kxr[11];
#pragma unroll
    for (int i = 0; i < 11; ++i) kxr[i] = kxn[i];

    const float* xb = xg + (size_t)b * T_ * X_;
    const float* yb = yg + (size_t)b * T_ * X_;

    // stage task mapping: 192 tasks (16 rows x 12 float4-quads), 48 active lanes/wave
    const bool sAct = (tid & 3) != 3;
    const int  sp   = (tid >> 2) * 3 + (tid & 3);
    const int  s_rr = sp / 12;
    const int  s_q  = sp - s_rr * 12;

    auto stage_load = [&](int r, float4& xv, float4& yv) {
        xv = make_float4(0.f, 0.f, 0.f, 0.f);
        yv = make_float4(0.f, 0.f, 0.f, 0.f);
        if (sAct) {
            int grow = t0 - 56 + 16 * r + s_rr;
            int gcol = x0 - 8 + 4 * s_q;
            if (grow >= 0 && grow < T_ && gcol >= 0 && gcol < X_) {
                xv = *(const float4*)(xb + (size_t)grow * X_ + gcol);
                yv = *(const float4*)(yb + (size_t)grow * X_ + gcol);
            }
        }
    };
    auto stage_write = [&](const float4& xv, const float4& yv) {
        if (sAct) {
            float xa[4] = {xv.x, xv.y, xv.z, xv.w};
            float ya[4] = {yv.x, yv.y, yv.z, yv.w};
            short4v o0, o1, o2, o3, o4;
#pragma unroll
            for (int k = 0; k < 4; ++k) {
                o0[k] = (short)f2bf(xa[k]);
                o1[k] = (short)f2bf(ya[k]);
                o2[k] = (short)f2bf(xa[k] * xa[k]);
                o3[k] = (short)f2bf(ya[k] * ya[k]);
                o4[k] = (short)f2bf(xa[k] * ya[k]);
            }
            *(short4v*)&PB[0][s_rr][4 * s_q] = o0;
            *(short4v*)&PB[1][s_rr][4 * s_q] = o1;
            *(short4v*)&PB[2][s_rr][4 * s_q] = o2;
            *(short4v*)&PB[3][s_rr][4 * s_q] = o3;
            *(short4v*)&PB[4][s_rr][4 * s_q] = o4;
        }
    };
    // xconv: 320 tasks (5f x 16 rows x 4 col-groups of 8); 11-tap VALU conv, ring write
    auto xconv = [&](int r) {
#pragma unroll
        for (int e = 0; e < 2; ++e) {
            int p; bool act;
            if (e == 0) { p = tid; act = true; }
            else { p = 256 + (tid >> 2); act = ((tid & 3) == 0); }
            if (act) {
                int f  = p >> 6;
                int rr = (p & 63) >> 2;
                int cg = p & 3;
                int rel  = 16 * r + rr;
                int slot = (rel >> 3) & 15;
                int rs   = rel & 7;
                short8 v0 = *(const short8*)&PB[f][rr][8 * cg];
                short8 v1 = *(const short8*)&PB[f][rr][8 * cg + 8];
                short8 v2 = *(const short8*)&PB[f][rr][8 * cg + 16];
                float val[18];
#pragma unroll
                for (int i = 0; i < 5; ++i) val[i] = bf2f((ushort)v0[3 + i]);
#pragma unroll
                for (int i = 0; i < 8; ++i) val[5 + i] = bf2f((ushort)v1[i]);
#pragma unroll
                for (int i = 0; i < 5; ++i) val[13 + i] = bf2f((ushort)v2[i]);
#pragma unroll
                for (int o = 0; o < 8; ++o) {
                    float a = 0.f;
#pragma unroll
                    for (int i = 0; i < 11; ++i) a = fmaf(kxr[i], val[o + i], a);
                    XS[slot][f][pcol(8 * cg + o)][rs] = (short)f2bf(a);
                }
            }
        }
    };

    // ---- prologue: fill ring with rel rows 0..127 (abs t0-56 .. t0+71) ----
    for (int r = 0; r < 8; ++r) {
        float4 xv, yv;
        stage_load(r, xv, yv);
        stage_write(xv, yv);
        __syncthreads();
        xconv(r);
        __syncthreads();
    }

    float local = 0.f;

    // ---- main loop: one 16-row output strip per iteration ----
    for (int m = 0; m < nm; ++m) {
        float4 xv, yv;
        stage_load(m + 8, xv, yv);   // issue early; consumed after barrier

        // tconv: 10 (n,f) tasks over 4 waves; acc over 4 K-chunks; D -> TS
        for (int Tt = w; Tt < 10; Tt += 4) {
            int n = Tt & 1, f = Tt >> 1;
            f32x4 acc; acc[0] = 0.f; acc[1] = 0.f; acc[2] = 0.f; acc[3] = 0.f;
#pragma unroll
            for (int c = 0; c < 4; ++c) {
                const short8 bfrag =
                    *(const short8*)&XS[(2 * m + 4 * c + g) & 15][f][pcol(16 * n + ln16)][0];
                acc = __builtin_amdgcn_mfma_f32_16x16x32_bf16(a_t[c], bfrag, acc, 0, 0, 0);
            }
#pragma unroll
            for (int r2 = 0; r2 < 4; ++r2)
                TS[f][4 * g + r2][16 * n + ln16] = acc[r2];
        }
        __syncthreads();

        stage_write(xv, yv);
        __syncthreads();

        xconv(m + 8);   // writes ring slots (2m)&15,(2m+1)&15 — free until strip m+1

        // pointwise coherence from TS
#pragma unroll
        for (int e = 0; e < 2; ++e) {
            int o = tid + 256 * e;
            int row = o >> 5, col = o & 31;
            int t = t0 + 16 * m + row;
            if (t < t_end) {
                float mux = TS[0][row][col], muy = TS[1][row][col];
                float vx  = TS[2][row][col] - mux * mux;
                float vy  = TS[3][row][col] - muy * muy;
                float cxy = TS[4][row][col] - mux * muy;
                local += 1.0f - cxy * rsqrtf(vx * vy + 1e-9f);
            }
        }
        __syncthreads();
    }

    // ---- block reduction ----
#pragma unroll
    for (int off = 32; off >= 1; off >>= 1) local += __shfl_down(local, off);
    if ((tid & 63) == 0) wred[tid >> 6] = local;
    __syncthreads();
    if (tid == 0)
        partial[((size_t)b * SEGS + seg) * NSX + blockIdx.x] =
            wred[0] + wred[1] + wred[2] + wred[3];
}

__global__ __launch_bounds__(256) void coh_reduce(const float* __restrict__ partial,
                                                  float* __restrict__ out) {
    __shared__ float wred[4];
    const int tid = threadIdx.x;
    float s = 0.0f;
    for (int i = tid; i < NBLK; i += 256) s += partial[i];
#pragma unroll
    for (int off = 32; off >= 1; off >>= 1) s += __shfl_down(s, off);
    if ((tid & 63) == 0) wred[tid >> 6] = s;
    __syncthreads();
    if (tid == 0)
        out[0] = (wred[0] + wred[1] + wred[2] + wred[3]) *
                 (1.0f / ((float)B_ * (float)T_ * (float)X_));
}

extern "C" void kernel_launch(void* const* d_in, const int* in_sizes, int n_in,
                              void* d_out, int out_size, void* d_ws, size_t ws_size,
                              hipStream_t stream) {
    const float* x = (const float*)d_in[0];
    const float* y = (const float*)d_in[1];
    float* out = (float*)d_out;
    float* partial = (float*)d_ws;   // NBLK floats = 4 KB

    dim3 grid(NSX, SEGS, B_);        // 16 x 4 x 16 = 1024 blocks
    coh3<<<grid, 256, 0, stream>>>(x, y, partial);
    coh_reduce<<<1, 256, 0, stream>>>(partial, out);
}

// Round 4
// 116.981 us; speedup vs baseline: 2.6841x; 1.7555x over previous
//
#include <hip/hip_runtime.h>
#include <hip/hip_bf16.h>

#define B_   16
#define T_   2500
#define X_   512
#define XT   32
#define SEGS 4
#define SEGR 640
#define NSX  (X_ / XT)            // 16
#define NBLK (B_ * SEGS * NSX)    // 1024

typedef __attribute__((ext_vector_type(4))) float f32x4;
typedef __attribute__((ext_vector_type(4))) ushort us4;

__device__ __forceinline__ ushort f2bf(float f) {
    __hip_bfloat16 h = __float2bfloat16(f);
    return __builtin_bit_cast(ushort, h);
}
__device__ __forceinline__ float bf2f(ushort u) {
    return __builtin_bit_cast(float, ((uint)u) << 16);
}

// Round-4 structure: 1 barrier/iter, wave-pair role alternation, fp8 ring.
//  Block = (32-col x-tile, 640-row T-segment, batch). 256 thr = 2 wave-pairs.
//  Per iteration `it` (chunk = 16 input rows):
//   producer pair: issue global loads(chunk it) -> regs; xconv(chunk it-1) from
//     PB (bf16) -> fp8 ring slots (2it-2, 2it-1)%18; vmcnt; products(it) -> PB.
//   consumer pair (it>=9, m=it-9): 5 fields x 4 K-chunks fp8 MFMA reading ring
//     slots (2m+4c+g)%18; in-register pointwise coherence (D: col=lane&15,
//     row=4*(lane>>4)+r). Roles swap each iteration (SIMD load balance).
//  Ring live window = 16 read + 2 written slots = 18, disjoint each phase.
__global__ __launch_bounds__(256, 4) void coh4(const float* __restrict__ xg,
                                               const float* __restrict__ yg,
                                               float* __restrict__ partial)
{
    __shared__ float ktn[104];
    __shared__ float kxn[12];
    __shared__ float norm2[2];
    __shared__ unsigned long long XS[18][5][34];   // fp8 ring: byte rs of [slot][f][col] = rowslot
    __shared__ ushort PB[5][16][52];               // bf16 raw products, one 16-row chunk
    __shared__ float wred[4];

    const int tid  = threadIdx.x;
    const int lane = tid & 63;
    const int w    = tid >> 6;
    const int g    = lane >> 4;
    const int ln16 = lane & 15;
    const int pair = w >> 1;        // wave-pair 0/1
    const int p01  = w & 1;         // index within pair
    const int prow = lane & 7;      // producer: row within 8-row half
    const int pcg  = lane >> 3;     // producer: col-group (6 cols stage / 4-col quad xconv)

    const int x0    = blockIdx.x * XT;
    const int seg   = blockIdx.y;
    const int t0    = seg * SEGR;
    const int t_end = min(t0 + SEGR, T_);
    const int nm    = (t_end - t0 + 15) >> 4;
    const int b     = blockIdx.z;

    // ---- normalized Gaussian tables ----
    if (tid < 104) ktn[tid] = 0.0f;
    if (tid < 12)  kxn[tid] = 0.0f;
    __syncthreads();
    if (tid < 101) { float d = (float)(tid - 50); ktn[tid] = expf(-d * d / (2.0f * 21.0f * 21.0f)); }
    if (tid < 11)  { float d = (float)(tid - 5);  kxn[tid] = expf(-d * d / (2.0f * 11.0f * 11.0f)); }
    __syncthreads();
    if (tid == 0) {
        float s = 0.f; for (int i = 0; i < 101; ++i) s += ktn[i]; norm2[0] = 1.0f / s;
        s = 0.f;       for (int i = 0; i < 11;  ++i) s += kxn[i]; norm2[1] = 1.0f / s;
    }
    __syncthreads();
    if (tid < 101) ktn[tid] *= norm2[0];
    if (tid < 11)  kxn[tid] *= norm2[1];
    __syncthreads();

    // ---- T-conv A fragments: kt band scaled x16, packed fp8 e4m3 ----
    // slot convention (A and B identical): slot sl of lane-group g <-> k = 32c+8g+sl
    long a_t[4];
#pragma unroll
    for (int c = 0; c < 4; ++c) {
        float vv[8];
#pragma unroll
        for (int sl = 0; sl < 8; ++sl) {
            int idx = 32 * c + 8 * g + sl - ln16 - 6;
            vv[sl] = (idx >= 0 && idx <= 100) ? ktn[idx] * 16.0f : 0.0f;
        }
        int lo = __builtin_amdgcn_cvt_pk_fp8_f32(vv[0], vv[1], 0, false);
        lo     = __builtin_amdgcn_cvt_pk_fp8_f32(vv[2], vv[3], lo, true);
        int hi = __builtin_amdgcn_cvt_pk_fp8_f32(vv[4], vv[5], 0, false);
        hi     = __builtin_amdgcn_cvt_pk_fp8_f32(vv[6], vv[7], hi, true);
        a_t[c] = (long)(((unsigned long long)(unsigned)hi << 32) | (unsigned)lo);
    }
    float kxr[11];
#pragma unroll
    for (int i = 0; i < 11; ++i) kxr[i] = kxn[i];

    const float* xb = xg + (size_t)b * T_ * X_;
    const float* yb = yg + (size_t)b * T_ * X_;

    float local = 0.f;
    int gbase = 0;                  // (2*it) % 18
    const int itmax = nm + 8;

    for (int it = 0; it <= itmax; ++it) {
        if (pair != (it & 1)) {
            // ================= producer =================
            const bool doLd = (it <= nm + 6);
            const int  rr   = 8 * p01 + prow;           // PB row this lane owns
            // 1) issue global loads for chunk `it`
            float2 xv[3], yv[3];
            {
                int grow = t0 - 56 + 16 * it + rr;
                bool rowOK = doLd && (grow >= 0) && (grow < T_);
                const float* xr = xb + (size_t)grow * X_;
                const float* yr = yb + (size_t)grow * X_;
#pragma unroll
                for (int d = 0; d < 3; ++d) {
                    int acol = x0 - 10 + 6 * pcg + 2 * d;
                    bool ok = rowOK && (acol >= 0) && (acol < X_);
                    xv[d] = ok ? *(const float2*)(xr + acol) : make_float2(0.f, 0.f);
                    yv[d] = ok ? *(const float2*)(yr + acol) : make_float2(0.f, 0.f);
                }
            }
            // 2) xconv of chunk it-1 (PB) -> fp8 ring (hides load latency)
            if (it >= 1 && it <= nm + 7) {
                int u = gbase + 16 + p01; if (u >= 18) u -= 18;   // slot of group 2(it-1)+p01
#pragma unroll
                for (int f = 0; f < 5; ++f) {
                    const us4 s0 = *(const us4*)&PB[f][rr][4 * pcg + 4];
                    const us4 s1 = *(const us4*)&PB[f][rr][4 * pcg + 8];
                    const us4 s2 = *(const us4*)&PB[f][rr][4 * pcg + 12];
                    const us4 s3 = *(const us4*)&PB[f][rr][4 * pcg + 16];
                    float v[16];
#pragma unroll
                    for (int j = 0; j < 4; ++j) {
                        v[j]      = bf2f((ushort)s0[j]);
                        v[4 + j]  = bf2f((ushort)s1[j]);
                        v[8 + j]  = bf2f((ushort)s2[j]);
                        v[12 + j] = bf2f((ushort)s3[j]);
                    }
                    float o[4];
#pragma unroll
                    for (int q = 0; q < 4; ++q) {
                        float a = 0.f;
#pragma unroll
                        for (int i = 0; i < 11; ++i) a = fmaf(kxr[i], v[q + 1 + i], a);
                        o[q] = a;
                    }
                    int pk = __builtin_amdgcn_cvt_pk_fp8_f32(o[0], o[1], 0, false);
                    pk     = __builtin_amdgcn_cvt_pk_fp8_f32(o[2], o[3], pk, true);
                    uchar* colp = (uchar*)&XS[u][f][4 * pcg];
                    colp[prow]      = (uchar)pk;
                    colp[8 + prow]  = (uchar)(pk >> 8);
                    colp[16 + prow] = (uchar)(pk >> 16);
                    colp[24 + prow] = (uchar)(pk >> 24);
                }
            }
            // 3) products of chunk `it` -> PB (consumes the loads)
            if (doLd) {
#pragma unroll
                for (int d = 0; d < 3; ++d) {
                    float ax = xv[d].x, bx = xv[d].y, ay = yv[d].x, by = yv[d].y;
                    int p = 6 * pcg + 2 * d;
                    *(uint*)&PB[0][rr][p] = (uint)f2bf(ax)      | ((uint)f2bf(bx)      << 16);
                    *(uint*)&PB[1][rr][p] = (uint)f2bf(ay)      | ((uint)f2bf(by)      << 16);
                    *(uint*)&PB[2][rr][p] = (uint)f2bf(ax * ax) | ((uint)f2bf(bx * bx) << 16);
                    *(uint*)&PB[3][rr][p] = (uint)f2bf(ay * ay) | ((uint)f2bf(by * by) << 16);
                    *(uint*)&PB[4][rr][p] = (uint)f2bf(ax * ay) | ((uint)f2bf(bx * by) << 16);
                }
            }
        } else if (it >= 9) {
            // ================= consumer =================
            const int m = it - 9;
            f32x4 acc[5];
#pragma unroll
            for (int f = 0; f < 5; ++f) { acc[f][0] = 0.f; acc[f][1] = 0.f; acc[f][2] = 0.f; acc[f][3] = 0.f; }
#pragma unroll
            for (int c = 0; c < 4; ++c) {
                int u = gbase + 4 * c + g; if (u >= 18) u -= 18;   // slot of group 2m+4c+g
#pragma unroll
                for (int f = 0; f < 5; ++f) {
                    long bfrag = (long)XS[u][f][16 * p01 + ln16];
                    acc[f] = __builtin_amdgcn_mfma_f32_16x16x32_fp8_fp8(a_t[c], bfrag, acc[f], 0, 0, 0);
                }
            }
            const float sc = 0.0625f;   // undo kt x16 scaling
#pragma unroll
            for (int r = 0; r < 4; ++r) {
                int t = t0 + 16 * m + 4 * g + r;
                if (t < t_end) {
                    float mux = acc[0][r] * sc, muy = acc[1][r] * sc;
                    float vx  = acc[2][r] * sc - mux * mux;
                    float vy  = acc[3][r] * sc - muy * muy;
                    float cxy = acc[4][r] * sc - mux * muy;
                    local += 1.0f - cxy * rsqrtf(vx * vy + 1e-9f);
                }
            }
        }
        __syncthreads();
        gbase += 2; if (gbase >= 18) gbase -= 18;
    }

    // ---- block reduction ----
#pragma unroll
    for (int off = 32; off >= 1; off >>= 1) local += __shfl_down(local, off);
    if ((tid & 63) == 0) wred[tid >> 6] = local;
    __syncthreads();
    if (tid == 0)
        partial[((size_t)b * SEGS + seg) * NSX + blockIdx.x] =
            wred[0] + wred[1] + wred[2] + wred[3];
}

__global__ __launch_bounds__(256) void coh_reduce(const float* __restrict__ partial,
                                                  float* __restrict__ out) {
    __shared__ float wred[4];
    const int tid = threadIdx.x;
    float s = 0.0f;
    for (int i = tid; i < NBLK; i += 256) s += partial[i];
#pragma unroll
    for (int off = 32; off >= 1; off >>= 1) s += __shfl_down(s, off);
    if ((tid & 63) == 0) wred[tid >> 6] = s;
    __syncthreads();
    if (tid == 0)
        out[0] = (wred[0] + wred[1] + wred[2] + wred[3]) *
                 (1.0f / ((float)B_ * (float)T_ * (float)X_));
}

extern "C" void kernel_launch(void* const* d_in, const int* in_sizes, int n_in,
                              void* d_out, int out_size, void* d_ws, size_t ws_size,
                              hipStream_t stream) {
    const float* x = (const float*)d_in[0];
    const float* y = (const float*)d_in[1];
    float* out = (float*)d_out;
    float* partial = (float*)d_ws;   // NBLK floats = 4 KB

    dim3 grid(NSX, SEGS, B_);        // 16 x 4 x 16 = 1024 blocks
    coh4<<<grid, 256, 0, stream>>>(x, y, partial);
    coh_reduce<<<1, 256, 0, stream>>>(partial, out);
}